// Round 12
// baseline (283.270 us; speedup 1.0000x reference)
//
#include <hip/hip_runtime.h>
#include <hip/hip_bf16.h>
#include <math.h>

// N = 100000, E = 3.2M, F_in = 128, H = C = 16. int inputs arrive as int32.
//
// out[d] = dinv[d]*(sum_{s->d} u[s] + u[d]) + b,  u = dinv .* (h @ W).
// R3: global f32 atomics ~19.5G txn/s. R5: LDS f32 atomics ~3cy/lane.
// R6: sort->CSR->register gather. R7: bf16 messages. R8/R9: radix bin+swizzle.
// R10: pipelined gathers = 242us. R11 (global-reservation bin) REGRESSED:
//      scattered 200B runs over 12.8MB thrash L2 write-combining (WRITE 5x).
// R12: chunk-local counting sort — each block sorts its own chunk by bucket in
//      LDS and writes it back coalesced to the SAME location (WRITE = ideal);
//      sortcsr gathers each bucket's 256 chunk-runs (latency-hidden reads).

#define F_IN 128
#define H 16
#define NPB 128            // nodes per bucket
#define MAX_NB 800         // max buckets (N <= 102400)
#define NBLK 256           // chunks
#define BINT 1024          // binsort threads
#define SBUF_MAX 12800     // max edges per chunk (E/NBLK = 12.5K)
#define SMAX 4864          // max edges per bucket (mean 4096, +12 sigma)
#define PFD 6              // gather prefetch depth: 8 slots * 6 = 48 edges

typedef __hip_bfloat16 bf16;

__device__ __forceinline__ float bflo(unsigned v) { return __uint_as_float(v << 16); }
__device__ __forceinline__ float bfhi(unsigned v) { return __uint_as_float(v & 0xffff0000u); }

// ---- binsort: per-chunk counting sort by bucket, written back in place.
//      packed = (dst&127)<<17 | src. Aux: loff_t/cnt_t [chunk*MAX_NB + bucket].
__global__ void binsort_kernel(const int* __restrict__ src, const int* __restrict__ dst,
                               unsigned* __restrict__ packed, int* __restrict__ loff_t,
                               int* __restrict__ cnt_t, int E, int NB) {
    __shared__ int hist[MAX_NB];
    __shared__ int cur[MAX_NB];
    __shared__ int scan[1024];
    __shared__ unsigned sbuf[SBUF_MAX];
    int b = blockIdx.x;
    long long e0 = (long long)E * b / NBLK;
    long long e1 = (long long)E * (b + 1) / NBLK;
    int len = (int)(e1 - e0);
    int t = threadIdx.x;

    for (int i = t; i < NB; i += BINT) hist[i] = 0;
    __syncthreads();
    for (int i = t; i < len; i += BINT) atomicAdd(&hist[dst[e0 + i] >> 7], 1);
    __syncthreads();
    scan[t] = (t < NB) ? hist[t] : 0;
    __syncthreads();
    for (int off = 1; off < 1024; off <<= 1) {
        int v = (t >= off) ? scan[t - off] : 0;
        __syncthreads();
        scan[t] += v;
        __syncthreads();
    }
    if (t < NB) {
        int ex = scan[t] - hist[t];
        cur[t] = ex;
        loff_t[b * MAX_NB + t] = ex;
        cnt_t[b * MAX_NB + t] = hist[t];
    }
    __syncthreads();
    for (int i = t; i < len; i += BINT) {
        int d = dst[e0 + i];
        int bk = d >> 7;
        int p = atomicAdd(&cur[bk], 1);
        sbuf[p] = (unsigned)src[e0 + i] | ((unsigned)(d & 127) << 17);
    }
    __syncthreads();
    for (int i = t; i < len; i += BINT) packed[e0 + i] = sbuf[i];   // coalesced
}

// ---- bucket totals (sum of cnt_t column) + exclusive scan -> base[] ----
__global__ void bucketscan_kernel(const int* __restrict__ cnt_t, int* __restrict__ base, int NB) {
    __shared__ int s[1024];
    int t = threadIdx.x;
    int tot = 0;
    if (t < NB)
        for (int blk = 0; blk < NBLK; blk++) tot += cnt_t[blk * MAX_NB + t];  // coalesced over t
    if (tot > SMAX) tot = SMAX;
    s[t] = (t < NB) ? tot : 0;
    __syncthreads();
    for (int off = 1; off < 1024; off <<= 1) {
        int v = (t >= off) ? s[t - off] : 0;
        __syncthreads();
        s[t] += v;
        __syncthreads();
    }
    if (t < NB) base[t] = s[t] - tot;
    if (t == NB - 1) base[NB] = s[t];
}

// ---- sortcsr: gather bucket b's 256 chunk-runs -> LDS, counting-sort by node,
//      write dense sorted[], rowptr[], dinv[] ----
__global__ void sortcsr_kernel(const unsigned* __restrict__ packed, const int* __restrict__ loff_t,
                               const int* __restrict__ cnt_t, const int* __restrict__ base,
                               unsigned* __restrict__ sorted, int* __restrict__ rowptr,
                               float* __restrict__ dinv, int N, int E, int NB) {
    __shared__ unsigned raw[SMAX];
    __shared__ unsigned ssort[SMAX];
    __shared__ int c[NBLK], doff[NBLK];
    __shared__ int cnt[NPB], offs[NPB], cur[NPB];
    __shared__ int slen;
    int b = blockIdx.x;
    int T = blockDim.x;
    int t = threadIdx.x;

    if (t < NBLK) { c[t] = cnt_t[t * MAX_NB + b]; doff[t] = c[t]; }
    __syncthreads();
    for (int off = 1; off < NBLK; off <<= 1) {
        int v = 0;
        if (t < NBLK && t >= off) v = doff[t - off];
        __syncthreads();
        if (t < NBLK) doff[t] += v;
        __syncthreads();
    }
    if (t == NBLK - 1) slen = doff[t];
    __syncthreads();
    int len = slen;
    if (len > SMAX) len = SMAX;

    // copy runs: wave w handles chunks w, w+8, ...; lanes copy within a run
    int wv = t >> 6, ln = t & 63;
    for (int q = wv; q < NBLK; q += 8) {
        int cq = c[q];
        int dq = doff[q] - cq;
        long long s0 = (long long)E * q / NBLK;
        int so = (int)s0 + loff_t[q * MAX_NB + b];
        for (int i = ln; i < cq; i += 64) {
            int dp = dq + i;
            if (dp < SMAX) raw[dp] = packed[so + i];
        }
    }
    __syncthreads();

    // counting sort raw[0..len) by node-local id (p>>17)
    for (int i = t; i < NPB; i += T) cnt[i] = 0;
    __syncthreads();
    for (int i = t; i < len; i += T) atomicAdd(&cnt[raw[i] >> 17], 1);
    __syncthreads();
    if (t < NPB) offs[t] = cnt[t];
    __syncthreads();
    for (int off = 1; off < NPB; off <<= 1) {
        int v = 0;
        if (t < NPB && t >= off) v = offs[t - off];
        __syncthreads();
        if (t < NPB) offs[t] += v;
        __syncthreads();
    }
    int e0 = base[b];
    if (t < NPB) {
        int ex = offs[t] - cnt[t];
        cur[t] = ex;
        int node = b * NPB + t;
        if (node < N) {
            rowptr[node] = e0 + ex;
            dinv[node] = rsqrtf(1.0f + (float)cnt[t]);
        }
    }
    __syncthreads();
    for (int i = t; i < len; i += T) {
        unsigned p = raw[i];
        int pos = atomicAdd(&cur[p >> 17], 1);
        ssort[pos] = p;
    }
    __syncthreads();
    for (int i = t; i < len; i += T) sorted[e0 + i] = ssort[i];
    if (b == 0 && t == 0) rowptr[N] = base[NB];
}

// ---- u[i][j] = dinv[i] * sum_k x[i][k]*W1[k][j]  (bf16 out) ----
#define XPAD 132
__global__ void xw1_kernel(const float* __restrict__ x, const float* __restrict__ W1,
                           const float* __restrict__ dinv, bf16* __restrict__ u, int n) {
    __shared__ float sW1[F_IN * H];
    __shared__ float sx[16 * XPAD];
    for (int t = threadIdx.x; t < F_IN * H; t += blockDim.x) sW1[t] = W1[t];

    int basei = blockIdx.x * 16;
    for (int idx = threadIdx.x; idx < 512; idx += 256) {
        int r = idx >> 5;
        int kk = (idx & 31) << 2;
        int row = basei + r;
        float4 v = make_float4(0.f, 0.f, 0.f, 0.f);
        if (row < n) v = *(const float4*)(x + (size_t)row * F_IN + kk);
        *(float4*)(sx + r * XPAD + kk) = v;
    }
    __syncthreads();

    int r = threadIdx.x >> 4;
    int j = threadIdx.x & 15;
    int row = basei + r;
    if (row >= n) return;

    const float* xr = sx + r * XPAD;
    float acc = 0.0f;
#pragma unroll 16
    for (int k = 0; k < F_IN; k++) acc += xr[k] * sW1[k * H + j];
    u[(size_t)row * H + j] = __float2bfloat16(dinv[row] * acc);
}

// ================= pipelined gather core (shared by both layers) =============
#define GATHER_TILE(UVPTR)                                                      \
    int lane = threadIdx.x & 63;                                                \
    int wave = threadIdx.x >> 6;                                                \
    int j2 = lane & 7, g = lane >> 3;                                           \
    int nodeBase = blockIdx.x * 64 + wave * 16;                                 \
    int r0c = 0, r1c = 0;                                                       \
    unsigned svc[PFD]; unsigned uvc[PFD];                                       \
    {   int node = nodeBase;                                                    \
        if (node < N) { r0c = rowptr[node]; r1c = rowptr[node + 1]; }           \
        _Pragma("unroll")                                                       \
        for (int m = 0; m < PFD; m++) {                                         \
            int k = r0c + g + 8 * m;                                            \
            if (k < r1c) svc[m] = sorted[k];                                    \
        }                                                                       \
        _Pragma("unroll")                                                       \
        for (int m = 0; m < PFD; m++) {                                         \
            int k = r0c + g + 8 * m;                                            \
            if (k < r1c) uvc[m] = UVPTR[(size_t)(svc[m] & 0x1FFFF) * 8 + j2];   \
        }                                                                       \
    }                                                                           \
    for (int t = 0; t < 16; t++) {                                              \
        int r0n = 0, r1n = 0;                                                   \
        unsigned svn[PFD];                                                      \
        if (t < 15) {                                                           \
            int nn = nodeBase + t + 1;                                          \
            if (nn < N) { r0n = rowptr[nn]; r1n = rowptr[nn + 1]; }             \
            _Pragma("unroll")                                                   \
            for (int m = 0; m < PFD; m++) {                                     \
                int k = r0n + g + 8 * m;                                        \
                if (k < r1n) svn[m] = sorted[k];                                \
            }                                                                   \
        }                                                                       \
        float ax = 0.f, ay = 0.f;                                               \
        _Pragma("unroll")                                                       \
        for (int m = 0; m < PFD; m++) {                                         \
            int k = r0c + g + 8 * m;                                            \
            if (k < r1c) { ax += bflo(uvc[m]); ay += bfhi(uvc[m]); }            \
        }                                                                       \
        for (int k = r0c + g + 8 * PFD; k < r1c; k += 8) {                      \
            unsigned va = UVPTR[(size_t)(sorted[k] & 0x1FFFF) * 8 + j2];        \
            ax += bflo(va); ay += bfhi(va);                                     \
        }                                                                       \
        ax += __shfl_xor(ax, 8);  ay += __shfl_xor(ay, 8);                      \
        ax += __shfl_xor(ax, 16); ay += __shfl_xor(ay, 16);                     \
        ax += __shfl_xor(ax, 32); ay += __shfl_xor(ay, 32);                     \
        if (g == 0) {                                                           \
            tile[(wave * 16 + t) * 16 + 2 * j2] = ax;                           \
            tile[(wave * 16 + t) * 16 + 2 * j2 + 1] = ay;                       \
        }                                                                       \
        if (t < 15) {                                                           \
            r0c = r0n; r1c = r1n;                                               \
            _Pragma("unroll")                                                   \
            for (int m = 0; m < PFD; m++) {                                     \
                int k = r0n + g + 8 * m;                                        \
                svc[m] = svn[m];                                                \
                if (k < r1n) uvc[m] = UVPTR[(size_t)(svn[m] & 0x1FFFF) * 8 + j2]; \
            }                                                                   \
        }                                                                       \
    }

// ---- layer-1 gather + finalize ----
__global__ void gatherfin1_kernel(const unsigned* __restrict__ sorted, const int* __restrict__ rowptr,
                                  const bf16* __restrict__ u, const float* __restrict__ dinv,
                                  const float* __restrict__ b1, const float* __restrict__ W2,
                                  bf16* __restrict__ u2, int N) {
    __shared__ float tile[64 * 16];
    __shared__ float sW2[256];
    __shared__ float sb1[16];
    sW2[threadIdx.x] = W2[threadIdx.x];
    if (threadIdx.x < 16) sb1[threadIdx.x] = b1[threadIdx.x];

    const unsigned* uvp = (const unsigned*)u;
    GATHER_TILE(uvp)
    __syncthreads();

    int jj = threadIdx.x & 15;
    for (int rr = 0; rr < 4; rr++) {
        int rl = (threadIdx.x >> 4) + rr * 16;
        int node = blockIdx.x * 64 + rl;
        float h = 0.f, di = 0.f;
        if (node < N) {
            di = dinv[node];
            h = di * (tile[rl * 16 + jj] + __bfloat162float(u[(size_t)node * H + jj])) + sb1[jj];
            h = fmaxf(h, 0.f);
        }
        float acc2 = 0.f;
#pragma unroll
        for (int kk = 0; kk < 16; kk++) {
            float hk = __shfl(h, kk, 16);
            acc2 += hk * sW2[kk * 16 + jj];
        }
        if (node < N) u2[(size_t)node * H + jj] = __float2bfloat16(di * acc2);
    }
}

// ---- layer-2 gather + finalize: log_softmax -> out (f32) ----
__global__ void gatherfin2_kernel(const unsigned* __restrict__ sorted, const int* __restrict__ rowptr,
                                  const bf16* __restrict__ u2, const float* __restrict__ dinv,
                                  const float* __restrict__ b2, float* __restrict__ out, int N) {
    __shared__ float tile[64 * 16];
    __shared__ float sb2[16];
    if (threadIdx.x < 16) sb2[threadIdx.x] = b2[threadIdx.x];

    const unsigned* uvp = (const unsigned*)u2;
    GATHER_TILE(uvp)
    __syncthreads();

    int jj = threadIdx.x & 15;
    for (int rr = 0; rr < 4; rr++) {
        int rl = (threadIdx.x >> 4) + rr * 16;
        int node = blockIdx.x * 64 + rl;
        if (node >= N) continue;
        float di = dinv[node];
        float v = di * (tile[rl * 16 + jj] + __bfloat162float(u2[(size_t)node * H + jj])) + sb2[jj];

        float m = v;
#pragma unroll
        for (int off = 8; off >= 1; off >>= 1) m = fmaxf(m, __shfl_xor(m, off, 16));
        float ex = __expf(v - m);
        float s = ex;
#pragma unroll
        for (int off = 8; off >= 1; off >>= 1) s += __shfl_xor(s, off, 16);

        out[(size_t)node * H + jj] = v - m - __logf(s);
    }
}

extern "C" void kernel_launch(void* const* d_in, const int* in_sizes, int n_in,
                              void* d_out, int out_size, void* d_ws, size_t ws_size,
                              hipStream_t stream) {
    const float* x = (const float*)d_in[0];
    const int* edge_index = (const int*)d_in[1];
    const float* W1 = (const float*)d_in[2];
    const float* b1 = (const float*)d_in[3];
    const float* W2 = (const float*)d_in[4];
    const float* b2 = (const float*)d_in[5];
    float* out = (float*)d_out;

    const int N = in_sizes[0] / F_IN;        // 100000
    const int E = in_sizes[1] / 2;           // 3200000
    const int* src = edge_index;
    const int* dst = edge_index + E;
    const int NB = (N + NPB - 1) / NPB;      // 782

    // ws (4B units): dinv[N] | u[8N] | u2[8N] | packed[E] | sorted[E] |
    //                rowptr[N+1] | loff_t[NBLK*MAX_NB] | cnt_t[NBLK*MAX_NB] | base[NB+1]
    float* dinv = (float*)d_ws;
    bf16* u = (bf16*)(dinv + N);
    bf16* u2 = (bf16*)((unsigned*)u + (size_t)N * H / 2);
    unsigned* packed = (unsigned*)((unsigned*)u2 + (size_t)N * H / 2);
    unsigned* sorted = packed + E;
    int* rowptr = (int*)(sorted + E);
    int* loff_t = rowptr + N + 1;
    int* cnt_t = loff_t + (size_t)NBLK * MAX_NB;
    int* base = cnt_t + (size_t)NBLK * MAX_NB;

    binsort_kernel<<<NBLK, BINT, 0, stream>>>(src, dst, packed, loff_t, cnt_t, E, NB);
    bucketscan_kernel<<<1, 1024, 0, stream>>>(cnt_t, base, NB);
    sortcsr_kernel<<<NB, 512, 0, stream>>>(packed, loff_t, cnt_t, base, sorted, rowptr, dinv, N, E, NB);

    xw1_kernel<<<(N + 15) / 16, 256, 0, stream>>>(x, W1, dinv, u, N);
    gatherfin1_kernel<<<(N + 63) / 64, 256, 0, stream>>>(sorted, rowptr, u, dinv, b1, W2, u2, N);
    gatherfin2_kernel<<<(N + 63) / 64, 256, 0, stream>>>(sorted, rowptr, u2, dinv, b2, out, N);
}

// Round 13
// 234.263 us; speedup vs baseline: 1.2092x; 1.2092x over previous
//
#include <hip/hip_runtime.h>
#include <hip/hip_bf16.h>
#include <math.h>

// N = 100000, E = 3.2M, F_in = 128, H = C = 16. int inputs arrive as int32.
//
// out[d] = dinv[d]*(sum_{s->d} u[s] + u[d]) + b,  u = dinv .* (h @ W).
// R3: global f32 atomics ~19.5G txn/s. R5: LDS f32 atomics ~3cy/lane.
// R6: sort->CSR->register gather. R7: bf16 messages. R8: 2-pass radix bin.
// R9: XCD swizzle. R10: pipelined gathers = 242us (BEST). R11/R12 binning
// restructures both REGRESSED (write-amp / run-gather) -> reverted to R10.
// R13: R10 + uint2 gather lanes (4 ch/lane, 16 slots): halves VMEM instrs
//      and addr-VALU in the gather kernels.

#define F_IN 128
#define H 16
#define NPB 128            // nodes per bucket
#define MAX_NB 800         // max buckets (N <= 102400)
#define NBLK 256           // binning blocks (must match hist partition)
#define BINT 1024          // binning threads per block
#define SMAX 4864          // max edges per bucket (mean 4096, +12 sigma)
#define PFD 3              // prefetch depth: 16 slots * 3 = 48 edges covered

typedef __hip_bfloat16 bf16;

__device__ __forceinline__ float bflo(unsigned v) { return __uint_as_float(v << 16); }
__device__ __forceinline__ float bfhi(unsigned v) { return __uint_as_float(v & 0xffff0000u); }

// physical block -> logical block so logically-adjacent blocks (adjacent output
// runs in packed[]) land on the same XCD (XCD = physical % 8 round-robin).
__device__ __forceinline__ int swz(int p) { return (p & 7) * 32 + (p >> 3); }

// ---- pass A: per-block bucket histogram -> hist_t[bucket*NBLK + block] ----
__global__ void histA_kernel(const int* __restrict__ dst, int* __restrict__ hist_t,
                             int E, int NB) {
    __shared__ int h[MAX_NB];
    int b = swz(blockIdx.x);
    long long e0 = (long long)E * b / NBLK;
    long long e1 = (long long)E * (b + 1) / NBLK;
    for (int i = threadIdx.x; i < NB; i += BINT) h[i] = 0;
    __syncthreads();
    for (long long e = e0 + threadIdx.x; e < e1; e += BINT)
        atomicAdd(&h[dst[e] >> 7], 1);
    __syncthreads();
    for (int i = threadIdx.x; i < NB; i += BINT) hist_t[i * NBLK + b] = h[i];
}

// ---- pass B1: per-bucket exclusive scan over blocks + bucket totals ----
__global__ void colscan_kernel(int* __restrict__ hist_t, int* __restrict__ btot) {
    __shared__ int s[NBLK];
    int j = blockIdx.x;
    int t = threadIdx.x;
    int v = hist_t[j * NBLK + t];
    s[t] = v;
    __syncthreads();
    for (int off = 1; off < NBLK; off <<= 1) {
        int w = (t >= off) ? s[t - off] : 0;
        __syncthreads();
        s[t] += w;
        __syncthreads();
    }
    hist_t[j * NBLK + t] = s[t] - v;
    if (t == NBLK - 1) btot[j] = s[t];
}

// ---- pass B2: exclusive scan over bucket totals -> base[] ----
__global__ void bucketscan_kernel(const int* __restrict__ btot, int* __restrict__ base, int NB) {
    __shared__ int s[1024];
    int t = threadIdx.x;
    s[t] = (t < NB) ? btot[t] : 0;
    __syncthreads();
    for (int off = 1; off < 1024; off <<= 1) {
        int v = (t >= off) ? s[t - off] : 0;
        __syncthreads();
        s[t] += v;
        __syncthreads();
    }
    if (t < NB) base[t] = s[t] - btot[t];
    if (t == NB - 1) base[NB] = s[t];
}

// ---- pass C: place edges; packed = (dst&127)<<17 | src; LDS cursors only ----
__global__ void binC_kernel(const int* __restrict__ src, const int* __restrict__ dst,
                            const int* __restrict__ hist_t, const int* __restrict__ base,
                            unsigned* __restrict__ packed, int E, int NB) {
    __shared__ int pos[MAX_NB];
    int b = swz(blockIdx.x);
    long long e0 = (long long)E * b / NBLK;
    long long e1 = (long long)E * (b + 1) / NBLK;
    for (int i = threadIdx.x; i < NB; i += BINT)
        pos[i] = base[i] + hist_t[i * NBLK + b];
    __syncthreads();
    for (long long e = e0 + threadIdx.x; e < e1; e += BINT) {
        int d = dst[e];
        int bk = d >> 7;
        int p = atomicAdd(&pos[bk], 1);
        packed[p] = (unsigned)src[e] | ((unsigned)(d & 127) << 17);
    }
}

// ---- pass D: per-bucket LDS counting sort -> sorted[], rowptr[], dinv[] ----
__global__ void sortcsr_kernel(const unsigned* __restrict__ packed, const int* __restrict__ base,
                               unsigned* __restrict__ sorted, int* __restrict__ rowptr,
                               float* __restrict__ dinv, int N, int E) {
    __shared__ unsigned ssort[SMAX];
    __shared__ int cnt[NPB], offs[NPB], cur[NPB];
    int b = blockIdx.x;
    int e0 = base[b];
    int len = base[b + 1] - e0;
    if (len > SMAX) len = SMAX;
    int T = blockDim.x;

    for (int i = threadIdx.x; i < NPB; i += T) cnt[i] = 0;
    __syncthreads();
    for (int i = threadIdx.x; i < len; i += T)
        atomicAdd(&cnt[packed[e0 + i] >> 17], 1);
    __syncthreads();
    if (threadIdx.x < NPB) offs[threadIdx.x] = cnt[threadIdx.x];
    __syncthreads();
    for (int off = 1; off < NPB; off <<= 1) {
        int v = 0;
        if (threadIdx.x < NPB && threadIdx.x >= off) v = offs[threadIdx.x - off];
        __syncthreads();
        if (threadIdx.x < NPB) offs[threadIdx.x] += v;
        __syncthreads();
    }
    if (threadIdx.x < NPB) {
        int ex = offs[threadIdx.x] - cnt[threadIdx.x];
        cur[threadIdx.x] = ex;
        int node = b * NPB + threadIdx.x;
        if (node < N) {
            rowptr[node] = e0 + ex;
            dinv[node] = rsqrtf(1.0f + (float)cnt[threadIdx.x]);
        }
    }
    __syncthreads();
    for (int i = threadIdx.x; i < len; i += T) {
        unsigned p = packed[e0 + i];
        int pos = atomicAdd(&cur[p >> 17], 1);
        ssort[pos] = p;
    }
    __syncthreads();
    for (int i = threadIdx.x; i < len; i += T) sorted[e0 + i] = ssort[i];
    if (b == 0 && threadIdx.x == 0) rowptr[N] = E;
}

// ---- u[i][j] = dinv[i] * sum_k x[i][k]*W1[k][j]  (bf16 out) ----
#define XPAD 132
__global__ void xw1_kernel(const float* __restrict__ x, const float* __restrict__ W1,
                           const float* __restrict__ dinv, bf16* __restrict__ u, int n) {
    __shared__ float sW1[F_IN * H];
    __shared__ float sx[16 * XPAD];
    for (int t = threadIdx.x; t < F_IN * H; t += blockDim.x) sW1[t] = W1[t];

    int basei = blockIdx.x * 16;
    for (int idx = threadIdx.x; idx < 512; idx += 256) {
        int r = idx >> 5;
        int kk = (idx & 31) << 2;
        int row = basei + r;
        float4 v = make_float4(0.f, 0.f, 0.f, 0.f);
        if (row < n) v = *(const float4*)(x + (size_t)row * F_IN + kk);
        *(float4*)(sx + r * XPAD + kk) = v;
    }
    __syncthreads();

    int r = threadIdx.x >> 4;
    int j = threadIdx.x & 15;
    int row = basei + r;
    if (row >= n) return;

    const float* xr = sx + r * XPAD;
    float acc = 0.0f;
#pragma unroll 16
    for (int k = 0; k < F_IN; k++) acc += xr[k] * sW1[k * H + j];
    u[(size_t)row * H + j] = __float2bfloat16(dinv[row] * acc);
}

// ================= pipelined gather core (shared by both layers) =============
// lane = (channel-quad j4 0..3) x (slot g 0..15). Each lane loads uint2 =
// 4 bf16 channels. Depth-2 pipeline over the 16 nodes a wave owns:
// prefetch sorted[t+1] while consuming uv[t] issued last iteration.
#define GATHER_TILE(UVPTR)                                                      \
    int lane = threadIdx.x & 63;                                                \
    int wave = threadIdx.x >> 6;                                                \
    int j4 = lane & 3, g = lane >> 2;                                           \
    int nodeBase = blockIdx.x * 64 + wave * 16;                                 \
    int r0c = 0, r1c = 0;                                                       \
    unsigned svc[PFD]; uint2 uvc[PFD];                                          \
    {   int node = nodeBase;                                                    \
        if (node < N) { r0c = rowptr[node]; r1c = rowptr[node + 1]; }           \
        _Pragma("unroll")                                                       \
        for (int m = 0; m < PFD; m++) {                                         \
            int k = r0c + g + 16 * m;                                           \
            if (k < r1c) svc[m] = sorted[k];                                    \
        }                                                                       \
        _Pragma("unroll")                                                       \
        for (int m = 0; m < PFD; m++) {                                         \
            int k = r0c + g + 16 * m;                                           \
            if (k < r1c) uvc[m] = UVPTR[(size_t)(svc[m] & 0x1FFFF) * 4 + j4];   \
        }                                                                       \
    }                                                                           \
    for (int t = 0; t < 16; t++) {                                              \
        int r0n = 0, r1n = 0;                                                   \
        unsigned svn[PFD];                                                      \
        if (t < 15) {                                                           \
            int nn = nodeBase + t + 1;                                          \
            if (nn < N) { r0n = rowptr[nn]; r1n = rowptr[nn + 1]; }             \
            _Pragma("unroll")                                                   \
            for (int m = 0; m < PFD; m++) {                                     \
                int k = r0n + g + 16 * m;                                       \
                if (k < r1n) svn[m] = sorted[k];                                \
            }                                                                   \
        }                                                                       \
        float ax = 0.f, ay = 0.f, az = 0.f, aw = 0.f;                           \
        _Pragma("unroll")                                                       \
        for (int m = 0; m < PFD; m++) {                                         \
            int k = r0c + g + 16 * m;                                           \
            if (k < r1c) {                                                      \
                ax += bflo(uvc[m].x); ay += bfhi(uvc[m].x);                     \
                az += bflo(uvc[m].y); aw += bfhi(uvc[m].y);                     \
            }                                                                   \
        }                                                                       \
        for (int k = r0c + g + 16 * PFD; k < r1c; k += 16) {                    \
            uint2 va = UVPTR[(size_t)(sorted[k] & 0x1FFFF) * 4 + j4];           \
            ax += bflo(va.x); ay += bfhi(va.x);                                 \
            az += bflo(va.y); aw += bfhi(va.y);                                 \
        }                                                                       \
        ax += __shfl_xor(ax, 4);  ay += __shfl_xor(ay, 4);                      \
        az += __shfl_xor(az, 4);  aw += __shfl_xor(aw, 4);                      \
        ax += __shfl_xor(ax, 8);  ay += __shfl_xor(ay, 8);                      \
        az += __shfl_xor(az, 8);  aw += __shfl_xor(aw, 8);                      \
        ax += __shfl_xor(ax, 16); ay += __shfl_xor(ay, 16);                     \
        az += __shfl_xor(az, 16); aw += __shfl_xor(aw, 16);                     \
        ax += __shfl_xor(ax, 32); ay += __shfl_xor(ay, 32);                     \
        az += __shfl_xor(az, 32); aw += __shfl_xor(aw, 32);                     \
        if (g == 0) {                                                           \
            float* tp = &tile[(wave * 16 + t) * 16 + 4 * j4];                   \
            tp[0] = ax; tp[1] = ay; tp[2] = az; tp[3] = aw;                     \
        }                                                                       \
        if (t < 15) {                                                           \
            r0c = r0n; r1c = r1n;                                               \
            _Pragma("unroll")                                                   \
            for (int m = 0; m < PFD; m++) {                                     \
                int k = r0n + g + 16 * m;                                       \
                svc[m] = svn[m];                                                \
                if (k < r1n) uvc[m] = UVPTR[(size_t)(svn[m] & 0x1FFFF) * 4 + j4]; \
            }                                                                   \
        }                                                                       \
    }

// ---- layer-1 gather + finalize ----
__global__ void gatherfin1_kernel(const unsigned* __restrict__ sorted, const int* __restrict__ rowptr,
                                  const bf16* __restrict__ u, const float* __restrict__ dinv,
                                  const float* __restrict__ b1, const float* __restrict__ W2,
                                  bf16* __restrict__ u2, int N) {
    __shared__ float tile[64 * 16];
    __shared__ float sW2[256];
    __shared__ float sb1[16];
    sW2[threadIdx.x] = W2[threadIdx.x];
    if (threadIdx.x < 16) sb1[threadIdx.x] = b1[threadIdx.x];

    const uint2* uvp = (const uint2*)u;   // [node*4 + j4] channel quads
    GATHER_TILE(uvp)
    __syncthreads();

    int jj = threadIdx.x & 15;
    for (int rr = 0; rr < 4; rr++) {
        int rl = (threadIdx.x >> 4) + rr * 16;
        int node = blockIdx.x * 64 + rl;
        float h = 0.f, di = 0.f;
        if (node < N) {
            di = dinv[node];
            h = di * (tile[rl * 16 + jj] + __bfloat162float(u[(size_t)node * H + jj])) + sb1[jj];
            h = fmaxf(h, 0.f);
        }
        float acc2 = 0.f;
#pragma unroll
        for (int kk = 0; kk < 16; kk++) {
            float hk = __shfl(h, kk, 16);
            acc2 += hk * sW2[kk * 16 + jj];
        }
        if (node < N) u2[(size_t)node * H + jj] = __float2bfloat16(di * acc2);
    }
}

// ---- layer-2 gather + finalize: log_softmax -> out (f32) ----
__global__ void gatherfin2_kernel(const unsigned* __restrict__ sorted, const int* __restrict__ rowptr,
                                  const bf16* __restrict__ u2, const float* __restrict__ dinv,
                                  const float* __restrict__ b2, float* __restrict__ out, int N) {
    __shared__ float tile[64 * 16];
    __shared__ float sb2[16];
    if (threadIdx.x < 16) sb2[threadIdx.x] = b2[threadIdx.x];

    const uint2* uvp = (const uint2*)u2;
    GATHER_TILE(uvp)
    __syncthreads();

    int jj = threadIdx.x & 15;
    for (int rr = 0; rr < 4; rr++) {
        int rl = (threadIdx.x >> 4) + rr * 16;
        int node = blockIdx.x * 64 + rl;
        if (node >= N) continue;
        float di = dinv[node];
        float v = di * (tile[rl * 16 + jj] + __bfloat162float(u2[(size_t)node * H + jj])) + sb2[jj];

        float m = v;
#pragma unroll
        for (int off = 8; off >= 1; off >>= 1) m = fmaxf(m, __shfl_xor(m, off, 16));
        float ex = __expf(v - m);
        float s = ex;
#pragma unroll
        for (int off = 8; off >= 1; off >>= 1) s += __shfl_xor(s, off, 16);

        out[(size_t)node * H + jj] = v - m - __logf(s);
    }
}

extern "C" void kernel_launch(void* const* d_in, const int* in_sizes, int n_in,
                              void* d_out, int out_size, void* d_ws, size_t ws_size,
                              hipStream_t stream) {
    const float* x = (const float*)d_in[0];
    const int* edge_index = (const int*)d_in[1];
    const float* W1 = (const float*)d_in[2];
    const float* b1 = (const float*)d_in[3];
    const float* W2 = (const float*)d_in[4];
    const float* b2 = (const float*)d_in[5];
    float* out = (float*)d_out;

    const int N = in_sizes[0] / F_IN;        // 100000
    const int E = in_sizes[1] / 2;           // 3200000
    const int* src = edge_index;
    const int* dst = edge_index + E;
    const int NB = (N + NPB - 1) / NPB;      // 782

    // ws (4B units): dinv[N] | u[8N] | u2[8N] | packed[E] | sorted[E] |
    //                hist_t[MAX_NB*NBLK] | rowptr[N+1] | btot[NB] | base[NB+1]
    float* dinv = (float*)d_ws;
    bf16* u = (bf16*)(dinv + N);
    bf16* u2 = (bf16*)((unsigned*)u + (size_t)N * H / 2);
    unsigned* packed = (unsigned*)((unsigned*)u2 + (size_t)N * H / 2);
    unsigned* sorted = packed + E;
    int* hist_t = (int*)(sorted + E);
    int* rowptr = hist_t + (size_t)MAX_NB * NBLK;
    int* btot = rowptr + N + 1;
    int* base = btot + NB;

    histA_kernel<<<NBLK, BINT, 0, stream>>>(dst, hist_t, E, NB);
    colscan_kernel<<<NB, NBLK, 0, stream>>>(hist_t, btot);
    bucketscan_kernel<<<1, 1024, 0, stream>>>(btot, base, NB);
    binC_kernel<<<NBLK, BINT, 0, stream>>>(src, dst, hist_t, base, packed, E, NB);
    sortcsr_kernel<<<NB, 512, 0, stream>>>(packed, base, sorted, rowptr, dinv, N, E);

    xw1_kernel<<<(N + 15) / 16, 256, 0, stream>>>(x, W1, dinv, u, N);
    gatherfin1_kernel<<<(N + 63) / 64, 256, 0, stream>>>(sorted, rowptr, u, dinv, b1, W2, u2, N);
    gatherfin2_kernel<<<(N + 63) / 64, 256, 0, stream>>>(sorted, rowptr, u2, dinv, b2, out, N);
}